// Round 1
// baseline (116.051 us; speedup 1.0000x reference)
//
#include <hip/hip_runtime.h>
#include <hip/hip_bf16.h>
#include <cstdint>

typedef __attribute__((ext_vector_type(8))) short short8;
typedef __attribute__((ext_vector_type(8))) unsigned short ushort8;
typedef __attribute__((ext_vector_type(4))) float f32x4;

#define B_TRIALS 256
#define F_BINS   100
#define N_UNITS  512
#define P_CH     512
#define G_SESS   10
#define H_DIM    1024  // 2N

// f32 -> bf16 round-to-nearest-even (finite inputs)
__device__ __forceinline__ unsigned short f2bf(float f) {
  unsigned int u = __builtin_bit_cast(unsigned int, f);
  u += 0x7fffu + ((u >> 16) & 1u);
  return (unsigned short)(u >> 16);
}

// async global->LDS, 16B per lane; ldst must be wave-uniform (lane offset is HW-added)
__device__ __forceinline__ void gload16(const void* gsrc, void* ldst) {
  __builtin_amdgcn_global_load_lds(
      (const __attribute__((address_space(1))) unsigned int*)gsrc,
      (__attribute__((address_space(3))) unsigned int*)ldst, 16, 0, 0);
}

// src: [g][K][N] f32  ->  dst: [g][N][K] bf16   (32x32 LDS tiles)
__global__ void cast_transpose(const float* __restrict__ src,
                               unsigned short* __restrict__ dst,
                               int K, int N) {
  __shared__ float tile[32][33];
  int g = blockIdx.z;
  int n0 = blockIdx.x * 32, k0 = blockIdx.y * 32;
  const float* s = src + (size_t)g * K * N;
  unsigned short* d = dst + (size_t)g * N * K;
  int t = threadIdx.x;
  int r = t >> 3, c = (t & 7) * 4;
  float4 v = *(const float4*)(s + (size_t)(k0 + r) * N + n0 + c);
  tile[r][c + 0] = v.x; tile[r][c + 1] = v.y;
  tile[r][c + 2] = v.z; tile[r][c + 3] = v.w;
  __syncthreads();
  ushort4 o;
  o.x = f2bf(tile[c + 0][r]);
  o.y = f2bf(tile[c + 1][r]);
  o.z = f2bf(tile[c + 2][r]);
  o.w = f2bf(tile[c + 3][r]);
  *(ushort4*)(d + (size_t)(n0 + r) * K + k0 + c) = o;
}

// GEMM1: h[b,f,m] = softsign(x[b,f,:] . W1t[g][m][:] + b1[g][m]), bf16 out
// grid: (4 n-tiles, 256 trials), 256 threads (4 waves), tile M=112 N=256 K-step 64
__global__ __launch_bounds__(256, 2) void gemm1_kernel(
    const float* __restrict__ x, const int* __restrict__ eid,
    const unsigned short* __restrict__ W1t, const float* __restrict__ b1,
    unsigned short* __restrict__ h) {
  __shared__ __align__(16) unsigned short At[112 * 64];
  __shared__ __align__(16) unsigned short Bt[256 * 64];
  int b = blockIdx.y;
  int ncol0 = blockIdx.x * 256;
  int g = eid[b];
  int tid = threadIdx.x;
  int wv = tid >> 6, lane = tid & 63;
  int lr = lane & 15, lg = lane >> 4;
  int wcol0 = wv * 64;

  const unsigned short* Wg = W1t + (size_t)g * H_DIM * N_UNITS + (size_t)ncol0 * N_UNITS;
  const float* xg = x + (size_t)b * F_BINS * N_UNITS;

  f32x4 zero = {0.f, 0.f, 0.f, 0.f};
  f32x4 acc[7][4];
#pragma unroll
  for (int i = 0; i < 7; i++)
#pragma unroll
    for (int j = 0; j < 4; j++) acc[i][j] = zero;

  for (int k0 = 0; k0 < N_UNITS; k0 += 64) {
    __syncthreads();
    // B stage: 2048 16B-chunks? no: 256cols*64k*2B = 32KB = 2048 chunks -> 8 rounds
#pragma unroll
    for (int r8 = 0; r8 < 8; r8++) {
      int idx = r8 * 256 + tid;
      int col = idx >> 3, s = idx & 7;
      int ks = s ^ (col & 7);  // source pre-swizzle so swizzled-read sees right data
      gload16(Wg + (size_t)col * N_UNITS + k0 + ks * 8,
              &Bt[(r8 * 256 + (tid & 192)) * 8]);
    }
    // A stage: f32 x -> bf16, swizzled ds_write. 896 chunks -> 3.5 rounds
#pragma unroll
    for (int r4 = 0; r4 < 4; r4++) {
      int idx = r4 * 256 + tid;
      if (idx < 896) {
        int row = idx >> 3, ks = idx & 7;
        int srow = row < F_BINS ? row : F_BINS - 1;  // padded rows: garbage, never stored
        const float* px = xg + (size_t)srow * N_UNITS + k0 + ks * 8;
        float4 v0 = *(const float4*)px;
        float4 v1 = *(const float4*)(px + 4);
        ushort8 w;
        w[0] = f2bf(v0.x); w[1] = f2bf(v0.y); w[2] = f2bf(v0.z); w[3] = f2bf(v0.w);
        w[4] = f2bf(v1.x); w[5] = f2bf(v1.y); w[6] = f2bf(v1.z); w[7] = f2bf(v1.w);
        *(ushort8*)&At[row * 64 + ((ks ^ (row & 7)) * 8)] = w;
      }
    }
    asm volatile("s_waitcnt vmcnt(0) lgkmcnt(0)" ::: "memory");
    __syncthreads();
#pragma unroll
    for (int kk = 0; kk < 2; kk++) {
      int kslot = kk * 4 + lg;
      short8 af[7];
#pragma unroll
      for (int mf = 0; mf < 7; mf++) {
        int row = mf * 16 + lr;
        af[mf] = *(const short8*)&At[row * 64 + ((kslot ^ (row & 7)) * 8)];
      }
#pragma unroll
      for (int nf = 0; nf < 4; nf++) {
        int col = wcol0 + nf * 16 + lr;
        short8 bv = *(const short8*)&Bt[col * 64 + ((kslot ^ (col & 7)) * 8)];
#pragma unroll
        for (int mf = 0; mf < 7; mf++)
          acc[mf][nf] = __builtin_amdgcn_mfma_f32_16x16x32_bf16(af[mf], bv, acc[mf][nf], 0, 0, 0);
      }
    }
  }
  // epilogue: +b1, softsign, bf16 store
  float b1v[4];
#pragma unroll
  for (int nf = 0; nf < 4; nf++)
    b1v[nf] = b1[(size_t)g * H_DIM + ncol0 + wcol0 + nf * 16 + lr];
#pragma unroll
  for (int mf = 0; mf < 7; mf++) {
#pragma unroll
    for (int r = 0; r < 4; r++) {
      int row = mf * 16 + lg * 4 + r;
      if (row < F_BINS) {
        size_t ho = ((size_t)b * F_BINS + row) * H_DIM + ncol0 + wcol0 + lr;
#pragma unroll
        for (int nf = 0; nf < 4; nf++) {
          float v = acc[mf][nf][r] + b1v[nf];
          v = v / (1.0f + fabsf(v));
          h[ho + nf * 16] = f2bf(v);
        }
      }
    }
  }
}

// GEMM2: out[b,f,p] = h[b,f,:] . W2t[g][p][:] + b2[g][p], f32 out
// grid: (2 p-tiles, 256 trials)
__global__ __launch_bounds__(256, 2) void gemm2_kernel(
    const unsigned short* __restrict__ h, const int* __restrict__ eid,
    const unsigned short* __restrict__ W2t, const float* __restrict__ b2,
    float* __restrict__ out) {
  __shared__ __align__(16) unsigned short At[112 * 64];
  __shared__ __align__(16) unsigned short Bt[256 * 64];
  int b = blockIdx.y;
  int pcol0 = blockIdx.x * 256;
  int g = eid[b];
  int tid = threadIdx.x;
  int wv = tid >> 6, lane = tid & 63;
  int lr = lane & 15, lg = lane >> 4;
  int wcol0 = wv * 64;

  const unsigned short* Wg = W2t + (size_t)g * P_CH * H_DIM + (size_t)pcol0 * H_DIM;
  const unsigned short* hg = h + (size_t)b * F_BINS * H_DIM;

  f32x4 zero = {0.f, 0.f, 0.f, 0.f};
  f32x4 acc[7][4];
#pragma unroll
  for (int i = 0; i < 7; i++)
#pragma unroll
    for (int j = 0; j < 4; j++) acc[i][j] = zero;

  for (int k0 = 0; k0 < H_DIM; k0 += 64) {
    __syncthreads();
#pragma unroll
    for (int r8 = 0; r8 < 8; r8++) {
      int idx = r8 * 256 + tid;
      int col = idx >> 3, s = idx & 7;
      int ks = s ^ (col & 7);
      gload16(Wg + (size_t)col * H_DIM + k0 + ks * 8,
              &Bt[(r8 * 256 + (tid & 192)) * 8]);
    }
#pragma unroll
    for (int r4 = 0; r4 < 4; r4++) {
      int idx = r4 * 256 + tid;
      if (idx < 896) {  // wave-uniform: round 3 waves 2,3 fully skip
        int row = idx >> 3, s = idx & 7;
        int ks = s ^ (row & 7);
        int srow = row < F_BINS ? row : F_BINS - 1;
        gload16(hg + (size_t)srow * H_DIM + k0 + ks * 8,
                &At[(r4 * 256 + (tid & 192)) * 8]);
      }
    }
    asm volatile("s_waitcnt vmcnt(0) lgkmcnt(0)" ::: "memory");
    __syncthreads();
#pragma unroll
    for (int kk = 0; kk < 2; kk++) {
      int kslot = kk * 4 + lg;
      short8 af[7];
#pragma unroll
      for (int mf = 0; mf < 7; mf++) {
        int row = mf * 16 + lr;
        af[mf] = *(const short8*)&At[row * 64 + ((kslot ^ (row & 7)) * 8)];
      }
#pragma unroll
      for (int nf = 0; nf < 4; nf++) {
        int col = wcol0 + nf * 16 + lr;
        short8 bv = *(const short8*)&Bt[col * 64 + ((kslot ^ (col & 7)) * 8)];
#pragma unroll
        for (int mf = 0; mf < 7; mf++)
          acc[mf][nf] = __builtin_amdgcn_mfma_f32_16x16x32_bf16(af[mf], bv, acc[mf][nf], 0, 0, 0);
      }
    }
  }
  float b2v[4];
#pragma unroll
  for (int nf = 0; nf < 4; nf++)
    b2v[nf] = b2[(size_t)g * P_CH + pcol0 + wcol0 + nf * 16 + lr];
#pragma unroll
  for (int mf = 0; mf < 7; mf++) {
#pragma unroll
    for (int r = 0; r < 4; r++) {
      int row = mf * 16 + lg * 4 + r;
      if (row < F_BINS) {
        size_t oo = ((size_t)b * F_BINS + row) * P_CH + pcol0 + wcol0 + lr;
#pragma unroll
        for (int nf = 0; nf < 4; nf++)
          out[oo + nf * 16] = acc[mf][nf][r] + b2v[nf];
      }
    }
  }
}

extern "C" void kernel_launch(void* const* d_in, const int* in_sizes, int n_in,
                              void* d_out, int out_size, void* d_ws, size_t ws_size,
                              hipStream_t stream) {
  const float* x  = (const float*)d_in[0];
  const int* eid  = (const int*)d_in[1];
  const float* W1 = (const float*)d_in[2];
  const float* b1 = (const float*)d_in[3];
  const float* W2 = (const float*)d_in[4];
  const float* b2 = (const float*)d_in[5];
  float* out = (float*)d_out;

  // workspace layout (73,400,320 B total):
  unsigned short* W1t = (unsigned short*)d_ws;                    // [10][1024][512] bf16
  unsigned short* W2t = W1t + (size_t)G_SESS * H_DIM * N_UNITS;   // [10][512][1024] bf16
  unsigned short* h   = W2t + (size_t)G_SESS * P_CH * H_DIM;      // [256][100][1024] bf16

  cast_transpose<<<dim3(H_DIM / 32, N_UNITS / 32, G_SESS), 256, 0, stream>>>(W1, W1t, N_UNITS, H_DIM);
  cast_transpose<<<dim3(P_CH / 32, H_DIM / 32, G_SESS), 256, 0, stream>>>(W2, W2t, H_DIM, P_CH);
  gemm1_kernel<<<dim3(4, B_TRIALS), 256, 0, stream>>>(x, eid, W1t, b1, h);
  gemm2_kernel<<<dim3(2, B_TRIALS), 256, 0, stream>>>(h, eid, W2t, b2, out);
}

// Round 2
// 107.750 us; speedup vs baseline: 1.0770x; 1.0770x over previous
//
#include <hip/hip_runtime.h>
#include <hip/hip_bf16.h>
#include <cstdint>

typedef __attribute__((ext_vector_type(8))) short short8;
typedef __attribute__((ext_vector_type(8))) unsigned short ushort8;
typedef __attribute__((ext_vector_type(4))) float f32x4;

#define B_TRIALS 256
#define F_BINS   100
#define N_UNITS  512
#define P_CH     512
#define G_SESS   10
#define H_DIM    1024  // 2N

// f32 -> bf16 round-to-nearest-even (finite inputs)
__device__ __forceinline__ unsigned short f2bf(float f) {
  unsigned int u = __builtin_bit_cast(unsigned int, f);
  u += 0x7fffu + ((u >> 16) & 1u);
  return (unsigned short)(u >> 16);
}

// async global->LDS, 16B per lane; ldst must be wave-uniform (lane offset is HW-added)
__device__ __forceinline__ void gload16(const void* gsrc, void* ldst) {
  __builtin_amdgcn_global_load_lds(
      (const __attribute__((address_space(1))) unsigned int*)gsrc,
      (__attribute__((address_space(3))) unsigned int*)ldst, 16, 0, 0);
}

// one-time x f32 -> bf16 (8 elems/thread/iter, grid-stride)
__global__ void cast_x(const float* __restrict__ src,
                       unsigned short* __restrict__ dst, int n8) {
  int i = blockIdx.x * blockDim.x + threadIdx.x;
  int stride = gridDim.x * blockDim.x;
  for (; i < n8; i += stride) {
    float4 v0 = ((const float4*)src)[(size_t)i * 2];
    float4 v1 = ((const float4*)src)[(size_t)i * 2 + 1];
    ushort8 w;
    w[0] = f2bf(v0.x); w[1] = f2bf(v0.y); w[2] = f2bf(v0.z); w[3] = f2bf(v0.w);
    w[4] = f2bf(v1.x); w[5] = f2bf(v1.y); w[6] = f2bf(v1.z); w[7] = f2bf(v1.w);
    ((ushort8*)dst)[i] = w;
  }
}

// src: [g][K][N] f32  ->  dst: [g][N][K] bf16   (32x32 LDS tiles)
__global__ void cast_transpose(const float* __restrict__ src,
                               unsigned short* __restrict__ dst,
                               int K, int N) {
  __shared__ float tile[32][33];
  int g = blockIdx.z;
  int n0 = blockIdx.x * 32, k0 = blockIdx.y * 32;
  const float* s = src + (size_t)g * K * N;
  unsigned short* d = dst + (size_t)g * N * K;
  int t = threadIdx.x;
  int r = t >> 3, c = (t & 7) * 4;
  float4 v = *(const float4*)(s + (size_t)(k0 + r) * N + n0 + c);
  tile[r][c + 0] = v.x; tile[r][c + 1] = v.y;
  tile[r][c + 2] = v.z; tile[r][c + 3] = v.w;
  __syncthreads();
  ushort4 o;
  o.x = f2bf(tile[c + 0][r]);
  o.y = f2bf(tile[c + 1][r]);
  o.z = f2bf(tile[c + 2][r]);
  o.w = f2bf(tile[c + 3][r]);
  *(ushort4*)(d + (size_t)(n0 + r) * K + k0 + c) = o;
}

// GEMM1: h[b,f,m] = softsign(xb[b,f,:] . W1t[g][m][:] + b1[g][m]), bf16 out
// grid: (4 n-tiles, 256 trials), 256 threads (4 waves), tile M=112 N=256 K-step 64
__global__ __launch_bounds__(256, 2) void gemm1_kernel(
    const unsigned short* __restrict__ xb, const int* __restrict__ eid,
    const unsigned short* __restrict__ W1t, const float* __restrict__ b1,
    unsigned short* __restrict__ h) {
  __shared__ __align__(16) unsigned short At[112 * 64];
  __shared__ __align__(16) unsigned short Bt[256 * 64];
  int b = blockIdx.y;
  int ncol0 = blockIdx.x * 256;
  int g = eid[b];
  int tid = threadIdx.x;
  int wv = tid >> 6, lane = tid & 63;
  int lr = lane & 15, lg = lane >> 4;
  int wcol0 = wv * 64;

  const unsigned short* Wg = W1t + (size_t)g * H_DIM * N_UNITS + (size_t)ncol0 * N_UNITS;
  const unsigned short* xg = xb + (size_t)b * F_BINS * N_UNITS;

  f32x4 zero = {0.f, 0.f, 0.f, 0.f};
  f32x4 acc[7][4];
#pragma unroll
  for (int i = 0; i < 7; i++)
#pragma unroll
    for (int j = 0; j < 4; j++) acc[i][j] = zero;

  for (int k0 = 0; k0 < N_UNITS; k0 += 64) {
    __syncthreads();
    // B stage: 256 cols x 64 k x 2B = 32KB = 2048 16B-chunks -> 8 rounds
#pragma unroll
    for (int r8 = 0; r8 < 8; r8++) {
      int idx = r8 * 256 + tid;
      int col = idx >> 3, s = idx & 7;
      int ks = s ^ (col & 7);  // source pre-swizzle so swizzled-read sees right data
      gload16(Wg + (size_t)col * N_UNITS + k0 + ks * 8,
              &Bt[(r8 * 256 + (tid & 192)) * 8]);
    }
    // A stage: 112 rows x 64 k bf16 = 896 16B-chunks -> 3.5 rounds (all gload16)
#pragma unroll
    for (int r4 = 0; r4 < 4; r4++) {
      int idx = r4 * 256 + tid;
      if (idx < 896) {  // round 3: waves 2,3 fully skip (wave-uniform)
        int row = idx >> 3, s = idx & 7;
        int ks = s ^ (row & 7);
        int srow = row < F_BINS ? row : F_BINS - 1;  // pad rows: dup row 99, never stored
        gload16(xg + (size_t)srow * N_UNITS + k0 + ks * 8,
                &At[(r4 * 256 + (tid & 192)) * 8]);
      }
    }
    asm volatile("s_waitcnt vmcnt(0) lgkmcnt(0)" ::: "memory");
    __syncthreads();
#pragma unroll
    for (int kk = 0; kk < 2; kk++) {
      int kslot = kk * 4 + lg;
      short8 af[7];
#pragma unroll
      for (int mf = 0; mf < 7; mf++) {
        int row = mf * 16 + lr;
        af[mf] = *(const short8*)&At[row * 64 + ((kslot ^ (row & 7)) * 8)];
      }
#pragma unroll
      for (int nf = 0; nf < 4; nf++) {
        int col = wcol0 + nf * 16 + lr;
        short8 bv = *(const short8*)&Bt[col * 64 + ((kslot ^ (col & 7)) * 8)];
#pragma unroll
        for (int mf = 0; mf < 7; mf++)
          acc[mf][nf] = __builtin_amdgcn_mfma_f32_16x16x32_bf16(af[mf], bv, acc[mf][nf], 0, 0, 0);
      }
    }
  }
  // epilogue: +b1, softsign, bf16 store
  float b1v[4];
#pragma unroll
  for (int nf = 0; nf < 4; nf++)
    b1v[nf] = b1[(size_t)g * H_DIM + ncol0 + wcol0 + nf * 16 + lr];
#pragma unroll
  for (int mf = 0; mf < 7; mf++) {
#pragma unroll
    for (int r = 0; r < 4; r++) {
      int row = mf * 16 + lg * 4 + r;
      if (row < F_BINS) {
        size_t ho = ((size_t)b * F_BINS + row) * H_DIM + ncol0 + wcol0 + lr;
#pragma unroll
        for (int nf = 0; nf < 4; nf++) {
          float v = acc[mf][nf][r] + b1v[nf];
          v = v / (1.0f + fabsf(v));
          h[ho + nf * 16] = f2bf(v);
        }
      }
    }
  }
}

// GEMM2: out[b,f,p] = h[b,f,:] . W2t[g][p][:] + b2[g][p], f32 out
// grid: (2 p-tiles, 256 trials)
__global__ __launch_bounds__(256, 2) void gemm2_kernel(
    const unsigned short* __restrict__ h, const int* __restrict__ eid,
    const unsigned short* __restrict__ W2t, const float* __restrict__ b2,
    float* __restrict__ out) {
  __shared__ __align__(16) unsigned short At[112 * 64];
  __shared__ __align__(16) unsigned short Bt[256 * 64];
  int b = blockIdx.y;
  int pcol0 = blockIdx.x * 256;
  int g = eid[b];
  int tid = threadIdx.x;
  int wv = tid >> 6, lane = tid & 63;
  int lr = lane & 15, lg = lane >> 4;
  int wcol0 = wv * 64;

  const unsigned short* Wg = W2t + (size_t)g * P_CH * H_DIM + (size_t)pcol0 * H_DIM;
  const unsigned short* hg = h + (size_t)b * F_BINS * H_DIM;

  f32x4 zero = {0.f, 0.f, 0.f, 0.f};
  f32x4 acc[7][4];
#pragma unroll
  for (int i = 0; i < 7; i++)
#pragma unroll
    for (int j = 0; j < 4; j++) acc[i][j] = zero;

  for (int k0 = 0; k0 < H_DIM; k0 += 64) {
    __syncthreads();
#pragma unroll
    for (int r8 = 0; r8 < 8; r8++) {
      int idx = r8 * 256 + tid;
      int col = idx >> 3, s = idx & 7;
      int ks = s ^ (col & 7);
      gload16(Wg + (size_t)col * H_DIM + k0 + ks * 8,
              &Bt[(r8 * 256 + (tid & 192)) * 8]);
    }
#pragma unroll
    for (int r4 = 0; r4 < 4; r4++) {
      int idx = r4 * 256 + tid;
      if (idx < 896) {
        int row = idx >> 3, s = idx & 7;
        int ks = s ^ (row & 7);
        int srow = row < F_BINS ? row : F_BINS - 1;
        gload16(hg + (size_t)srow * H_DIM + k0 + ks * 8,
                &At[(r4 * 256 + (tid & 192)) * 8]);
      }
    }
    asm volatile("s_waitcnt vmcnt(0) lgkmcnt(0)" ::: "memory");
    __syncthreads();
#pragma unroll
    for (int kk = 0; kk < 2; kk++) {
      int kslot = kk * 4 + lg;
      short8 af[7];
#pragma unroll
      for (int mf = 0; mf < 7; mf++) {
        int row = mf * 16 + lr;
        af[mf] = *(const short8*)&At[row * 64 + ((kslot ^ (row & 7)) * 8)];
      }
#pragma unroll
      for (int nf = 0; nf < 4; nf++) {
        int col = wcol0 + nf * 16 + lr;
        short8 bv = *(const short8*)&Bt[col * 64 + ((kslot ^ (col & 7)) * 8)];
#pragma unroll
        for (int mf = 0; mf < 7; mf++)
          acc[mf][nf] = __builtin_amdgcn_mfma_f32_16x16x32_bf16(af[mf], bv, acc[mf][nf], 0, 0, 0);
      }
    }
  }
  float b2v[4];
#pragma unroll
  for (int nf = 0; nf < 4; nf++)
    b2v[nf] = b2[(size_t)g * P_CH + pcol0 + wcol0 + nf * 16 + lr];
#pragma unroll
  for (int mf = 0; mf < 7; mf++) {
#pragma unroll
    for (int r = 0; r < 4; r++) {
      int row = mf * 16 + lg * 4 + r;
      if (row < F_BINS) {
        size_t oo = ((size_t)b * F_BINS + row) * P_CH + pcol0 + wcol0 + lr;
#pragma unroll
        for (int nf = 0; nf < 4; nf++)
          out[oo + nf * 16] = acc[mf][nf][r] + b2v[nf];
      }
    }
  }
}

extern "C" void kernel_launch(void* const* d_in, const int* in_sizes, int n_in,
                              void* d_out, int out_size, void* d_ws, size_t ws_size,
                              hipStream_t stream) {
  const float* x  = (const float*)d_in[0];
  const int* eid  = (const int*)d_in[1];
  const float* W1 = (const float*)d_in[2];
  const float* b1 = (const float*)d_in[3];
  const float* W2 = (const float*)d_in[4];
  const float* b2 = (const float*)d_in[5];
  float* out = (float*)d_out;

  // workspace layout (73,400,320 B in d_ws):
  unsigned short* W1t = (unsigned short*)d_ws;                    // [10][1024][512] bf16
  unsigned short* W2t = W1t + (size_t)G_SESS * H_DIM * N_UNITS;   // [10][512][1024] bf16
  unsigned short* h   = W2t + (size_t)G_SESS * P_CH * H_DIM;      // [256][100][1024] bf16
  // xb (26.2MB bf16) lives in d_out (52.4MB): dead before gemm2 writes real output
  unsigned short* xb  = (unsigned short*)d_out;                   // [256][100][512] bf16

  cast_x<<<2048, 256, 0, stream>>>(x, xb, B_TRIALS * F_BINS * N_UNITS / 8);
  cast_transpose<<<dim3(H_DIM / 32, N_UNITS / 32, G_SESS), 256, 0, stream>>>(W1, W1t, N_UNITS, H_DIM);
  cast_transpose<<<dim3(P_CH / 32, H_DIM / 32, G_SESS), 256, 0, stream>>>(W2, W2t, H_DIM, P_CH);
  gemm1_kernel<<<dim3(4, B_TRIALS), 256, 0, stream>>>(xb, eid, W1t, b1, h);
  gemm2_kernel<<<dim3(2, B_TRIALS), 256, 0, stream>>>(h, eid, W2t, b2, out);
}